// Round 4
// baseline (12601.948 us; speedup 1.0000x reference)
//
#include <hip/hip_runtime.h>

typedef _Float16 f16;
typedef _Float16 f16x8 __attribute__((ext_vector_type(8)));
typedef float f32x4 __attribute__((ext_vector_type(4)));

#define MFMA16(a, b, c) __builtin_amdgcn_mfma_f32_16x16x32_f16((a), (b), (c), 0, 0, 0)

__device__ __forceinline__ float sigmoidf_(float x) { return 1.f / (1.f + __expf(-x)); }
__device__ __forceinline__ float tanhf_(float x) { return 1.f - 2.f / (__expf(2.f * x) + 1.f); }

// async global->LDS, 16B per lane; LDS dest is wave-uniform base + lane*16
__device__ __forceinline__ void gl_lds16(const void* g, void* l) {
    __builtin_amdgcn_global_load_lds(
        (__attribute__((address_space(1))) const unsigned int*)g,
        (__attribute__((address_space(3))) unsigned int*)l, 16, 0, 0);
}

// ---------------- workspace layout (bytes) ----------------
// pk (packed f16 weights)  0 .. 1998848
//   inW 0 | e0 16384 | e1 344064 | d0i 868352 | d0h 933888 | d1 950272 | out 983040 (f16 elem offs)
// biases  (2560 f32)       1998848
// cnt     (1024 i32)       2009088   [cnt0: 512, cnt1: 512]
// h0f     (12.8MB frag)    2013184   [grp 32][t 100][mt 2][kt 2][lane 64][8]
//   exch1 (1MB)            2013184   (aliases h0f; h0f dead when enc1 runs) [grp][slot 2][frag 16][lane][8]
//   zb    (0.5MB)          3061760   (aliases h0f) row-major [1024][256] f16
// h1x     (52.4MB frag)    15120384  [grp 32][t 100][mt 2][hkt 8][lane 64][8]  (enc0 h-out == enc1 x-in)
#define BIAS_OFF   1998848
#define CNT_OFF    2009088
#define H0F_OFF    2013184
#define EXCH1_OFF  2013184
#define Z_OFF      3061760
#define H1X_OFF    15120384

// Fragment convention (gfx950 16x16x32 f16): frag lane la, elem e:
//   A: row = la&15,         k = kt*32 + (la>>4)*8 + e
//   B: n   = nt*16+(la&15), k = kt*32 + (la>>4)*8 + e
//
// e-region pack layout (j-split for LDS-resident enc kernels):
//   [jslice 8][ntl 8 = gate*2+jh][kt KT][lane 64][8]   (block s's chunk = KT*8192 B, contiguous)
// other regions unchanged (nt-major).

__global__ __launch_bounds__(256) void pack_kernel(
    const float* inW,
    const float* e0i, const float* e0h, const float* e1i, const float* e1h,
    const float* d0i, const float* d0h, const float* d1i, const float* d1h,
    const float* outW,
    const float* eb0i, const float* eb0h, const float* eb1i, const float* eb1h,
    const float* db0i, const float* db0h, const float* db1i, const float* db1h,
    f16* pk, float* bias_ws, int* cnt_ws)
{
    int t = blockIdx.x * 256 + threadIdx.x;
    if (t < 124928) {
        int g = t; int KT, ka, kb, ktx; const float* A; const float* B; long doff;
        if (g < 2048)        {              KT = 8;  ka = 256; kb = 0;   ktx = -1; A = inW;  B = nullptr; doff = 0; }
        else if (g < 43008)  { g -= 2048;   KT = 10; ka = 64;  kb = 256; ktx = 2;  A = e0i;  B = e0h;     doff = 16384; }
        else if (g < 108544) { g -= 43008;  KT = 16; ka = 256; kb = 256; ktx = 8;  A = e1i;  B = e1h;     doff = 344064; }
        else if (g < 116736) { g -= 108544; KT = 8;  ka = 256; kb = 0;   ktx = -1; A = d0i;  B = nullptr; doff = 868352; }
        else if (g < 118784) { g -= 116736; KT = 2;  ka = 64;  kb = 0;   ktx = -1; A = d0h;  B = nullptr; doff = 933888; }
        else if (g < 122880) { g -= 118784; KT = 4;  ka = 64;  kb = 64;  ktx = -1; A = d1i;  B = d1h;     doff = 950272; }
        else                 { g -= 122880; KT = 2;  ka = 64;  kb = 0;   ktx = -1; A = outW; B = nullptr; doff = 983040; }
        int lane = g & 63; int gk = g >> 6;
        int n, k0;
        if (ktx >= 0) {
            int kt = gk % KT; int rest = gk / KT;
            int ntl = rest & 7, sj = rest >> 3;
            n  = (ntl >> 1) * 256 + sj * 32 + (ntl & 1) * 16 + (lane & 15);
            k0 = kt * 32 + (lane >> 4) * 8;
        } else {
            int kt = gk % KT; int nt = gk / KT;
            n  = nt * 16 + (lane & 15);
            k0 = kt * 32 + (lane >> 4) * 8;
        }
        f16x8 v;
        #pragma unroll
        for (int j = 0; j < 8; ++j) {
            int k = k0 + j;
            float s = (k < ka) ? A[(long)n * ka + k] : B[(long)n * kb + (k - ka)];
            v[j] = (f16)s;
        }
        *(f16x8*)(pk + doff + (long)g * 8) = v;
    } else if (t < 127488) {
        int i = t - 124928;
        if (i < 1024)      bias_ws[i] = eb0i[i] + eb0h[i];
        else if (i < 2048) bias_ws[i] = eb1i[i - 1024] + eb1h[i - 1024];
        else if (i < 2304) bias_ws[i] = db0i[i - 2048] + db0h[i - 2048];
        else               bias_ws[i] = db1i[i - 2304] + db1h[i - 2304];
    } else if (t < 128512) {
        cnt_ws[t - 127488] = 0;           // zero sync counters every launch (graph replay!)
    }
}

// h0f = relu(x @ inW^T + in_b) written in enc0's x-fragment layout.
// grid 6400 = 64 b-tiles x 100 t; block -> (btile, t); 4 waves, wave w -> n-tile w.
__global__ __launch_bounds__(256) void inproj_kernel(
    const float* __restrict__ x, const f16* __restrict__ pkInW,
    const float* __restrict__ in_b, f16* __restrict__ h0f)
{
    int bt = blockIdx.x / 100, t = blockIdx.x % 100;
    int tid = threadIdx.x;
    int l = tid & 63, w = tid >> 6;
    int p = l & 15, q = l >> 4;
    f32x4 acc = {0.f, 0.f, 0.f, 0.f};
    const float* xrow = x + ((size_t)(bt * 16 + p) * 100 + t) * 256 + q * 8;
    const f16x8* bp = (const f16x8*)pkInW + w * 8 * 64 + l;
    #pragma unroll
    for (int kt = 0; kt < 8; ++kt) {
        const float4* xa = (const float4*)(xrow + kt * 32);
        float4 x0 = xa[0], x1 = xa[1];
        f16x8 a = {(f16)x0.x, (f16)x0.y, (f16)x0.z, (f16)x0.w,
                   (f16)x1.x, (f16)x1.y, (f16)x1.z, (f16)x1.w};
        f16x8 b = bp[kt * 64];
        acc = MFMA16(a, b, acc);
    }
    int n = w * 16 + p;
    float bn = in_b[n];
    int grp = bt >> 1, mt = bt & 1, kt_o = w >> 1;
    int la = (((w & 1) * 2 + (p >> 3)) & 3) * 16 + q * 4;   // +r
    f16* op = h0f + (((size_t)grp * 100 + t) * 4 + mt * 2 + kt_o) * 512 + la * 8 + (p & 7);
    #pragma unroll
    for (int r = 0; r < 4; ++r) {
        float v = acc[r] + bn;
        v = v > 0.f ? v : 0.f;
        op[r * 8] = (f16)v;
    }
}

// LDS-resident j-split persistent LSTM layer.
// 256 blocks x 256 threads: block = (group grp of 32 batch rows, j-slice s of 32 cols).
// Weights for its 128 gate-outputs x K (=KTX*32 + 256) live in LDS (loaded once).
// Per ts: x-frags + peer h-frags -> registers (global, frag-major), 4*KT MFMAs/wave,
// in-lane pointwise, h-slice written to the exchange buffer, release-flag per wave.
// Peer sync: monotone per-group counter (32 wave-arrivals per ts), acquire-spin.
// Wave w: jh = w>>1 (j half), mt = w&1 (batch half). No intra-block barriers in the loop.
template <int KTX, bool E1>
__global__ __launch_bounds__(256, 1) void lstm_enc_kernel(
    const f16* __restrict__ xsrc,   // E1: h1x frag [grp][t][mt][kt 8]; else h0f [grp][t][mt][kt 2]
    const f16* __restrict__ pkW,    // [s][ntl 8][kt KT][lane][8]
    const float* __restrict__ bias, // [1024]
    f16* __restrict__ hxout,        // E1: exch1 ring; else h1x full-T
    const f16* __restrict__ hxin,   // same buffer (peer reads)
    f16* __restrict__ zout,         // E1: z row-major [1024][256]
    int* __restrict__ cnt)
{
    constexpr int KT = KTX + 8;
    constexpr int T = 100;
    __shared__ __align__(16) f16 Wl[8 * KT * 512];
    int tid = threadIdx.x;
    int l = tid & 63, w = tid >> 6;
    int p = l & 15, q = l >> 4;
    int jh = w >> 1, mt = w & 1;
    int bid = blockIdx.x;
    int c = bid & 7, k = bid >> 3;      // c = XCD under default round-robin (perf heuristic)
    int grp = c * 4 + (k >> 3);         // peer blocks of a group share an XCD
    int s = k & 7;

    // stage this block's weight slice into LDS (once)
    {
        const char* src = (const char*)pkW + (size_t)s * (KT * 8192);
        char* dst = (char*)Wl;
        #pragma unroll
        for (int r = 0; r < KT * 2; ++r)
            gl_lds16(src + r * 4096 + tid * 16, dst + r * 4096 + w * 1024);
    }
    float bs[4];
    #pragma unroll
    for (int g = 0; g < 4; ++g) bs[g] = bias[g * 256 + s * 32 + jh * 16 + p];
    float cc[4] = {0.f, 0.f, 0.f, 0.f};
    int* cp = cnt + grp * 16;
    __syncthreads();                    // drains weight staging

    for (int t = 0; t < T; ++t) {
        // x fragments -> regs (producer finished in a prior kernel; no flags needed)
        f16x8 xa[KTX];
        {
            constexpr int NF = E1 ? 16 : 4;
            const f16* xb = xsrc + (((size_t)grp * 100 + t) * NF + mt * (NF / 2)) * 512 + l * 8;
            #pragma unroll
            for (int i = 0; i < KTX; ++i) xa[i] = *(const f16x8*)(xb + i * 512);
        }
        // wait peers' h(t-1), then h fragments -> regs
        f16x8 ha[8];
        if (t > 0) {
            int need = 32 * t;
            while (__hip_atomic_load(cp, __ATOMIC_ACQUIRE, __HIP_MEMORY_SCOPE_AGENT) < need) {}
            size_t hbase = E1 ? ((size_t)grp * 2 + ((t - 1) & 1)) * 16
                              : ((size_t)grp * 100 + (t - 1)) * 16;
            const f16* hb = hxin + (hbase + mt * 8) * 512 + l * 8;
            #pragma unroll
            for (int i = 0; i < 8; ++i) ha[i] = *(const f16x8*)(hb + i * 512);
        }
        __builtin_amdgcn_sched_barrier(0);   // pin load issue above the MFMA stream

        f32x4 acc[4];
        #pragma unroll
        for (int g = 0; g < 4; ++g) acc[g] = (f32x4){0.f, 0.f, 0.f, 0.f};
        #pragma unroll
        for (int i = 0; i < KTX; ++i)
            #pragma unroll
            for (int g = 0; g < 4; ++g)
                acc[g] = MFMA16(xa[i],
                    *(const f16x8*)&Wl[(((g * 2 + jh) * KT + i) * 64 + l) * 8], acc[g]);
        if (t > 0) {
            #pragma unroll
            for (int i = 0; i < 8; ++i)
                #pragma unroll
                for (int g = 0; g < 4; ++g)
                    acc[g] = MFMA16(ha[i],
                        *(const f16x8*)&Wl[(((g * 2 + jh) * KT + KTX + i) * 64 + l) * 8], acc[g]);
        }
        // pointwise (in-lane: rows mt*16+q*4+r, col j = s*32+jh*16+p) + h-slice write
        int la = (jh * 2 + (p >> 3)) * 16 + q * 4;   // frag lane for (row, k_local=jh*16+p)
        size_t obase = E1 ? (((size_t)grp * 2 + (t & 1)) * 16 + mt * 8 + s)
                          : (((size_t)grp * 100 + t) * 16 + mt * 8 + s);
        f16* op = hxout + obase * 512 + la * 8 + (p & 7);
        #pragma unroll
        for (int r = 0; r < 4; ++r) {
            float iv = sigmoidf_(acc[0][r] + bs[0]);
            float fv = sigmoidf_(acc[1][r] + bs[1]);
            float gv = tanhf_(acc[2][r] + bs[2]);
            float ov = sigmoidf_(acc[3][r] + bs[3]);
            float cv = fv * cc[r] + iv * gv; cc[r] = cv;
            float hv = ov * tanhf_(cv);
            if (E1 && t == T - 1)
                zout[(size_t)(grp * 32 + mt * 16 + q * 4 + r) * 256 + s * 32 + jh * 16 + p] = (f16)hv;
            else
                op[r * 8] = (f16)hv;
        }
        if (t < T - 1) {
            __threadfence();            // agent-scope release of the slice stores
            if (l == 0)
                __hip_atomic_fetch_add(cp, 1, __ATOMIC_RELEASE, __HIP_MEMORY_SCOPE_AGENT);
        }
    }
}

// Fused decoder: dec0 (input z, constant over t -> xz in regs) + dec1 + output projection.
// 64 blocks x 256 threads (4 waves). hdfrag holds [h_d0 | h_d1] (K=128) fragment-major.
// All recurrent weights preloaded into registers -> inner loop is global-free.
__global__ __launch_bounds__(256, 1) void lstm_dec_kernel(
    const f16* __restrict__ z,
    const f16* __restrict__ pkD0i, const f16* __restrict__ pkD0h,
    const f16* __restrict__ pkD1,  const f16* __restrict__ pkOut,
    const float* __restrict__ bd0, const float* __restrict__ bd1,
    const float* __restrict__ out_b, float* __restrict__ out)
{
    constexpr int T = 100;
    __shared__ __align__(16) f16 hdfrag[4 * 64 * 8];
    int tid = threadIdx.x;
    int l = tid & 63, w = tid >> 6;
    int p = l & 15, q = l >> 4;
    int b0 = blockIdx.x * 16;

    for (int i = tid; i < 2048; i += 256) hdfrag[i] = (f16)0.f;

    f16x8 W0h[2][4], W1[4][4], WO[2][4];
    #pragma unroll
    for (int g = 0; g < 4; ++g) {
        #pragma unroll
        for (int kt = 0; kt < 2; ++kt)
            W0h[kt][g] = ((const f16x8*)pkD0h)[(((g * 4 + w) * 2 + kt) * 64) + l];
        #pragma unroll
        for (int kt = 0; kt < 4; ++kt)
            W1[kt][g] = ((const f16x8*)pkD1)[(((g * 4 + w) * 4 + kt) * 64) + l];
    }
    #pragma unroll
    for (int i = 0; i < 4; ++i)
        #pragma unroll
        for (int kt = 0; kt < 2; ++kt)
            WO[kt][i] = ((const f16x8*)pkOut)[(((w * 4 + i) * 2 + kt) * 64) + l];

    f32x4 xz[4];
    #pragma unroll
    for (int g = 0; g < 4; ++g) xz[g] = (f32x4){0.f, 0.f, 0.f, 0.f};
    {
        const f16x8* zp = (const f16x8*)z + (long)(b0 + p) * 32 + q;
        const f16x8* wp = (const f16x8*)pkD0i + l;
        #pragma unroll
        for (int kt = 0; kt < 8; ++kt) {
            f16x8 a = zp[kt * 4];
            #pragma unroll
            for (int g = 0; g < 4; ++g)
                xz[g] = MFMA16(a, wp[((g * 4 + w) * 8 + kt) * 64], xz[g]);
        }
        #pragma unroll
        for (int g = 0; g < 4; ++g) {
            float bb = bd0[g * 64 + w * 16 + p];
            #pragma unroll
            for (int r = 0; r < 4; ++r) xz[g][r] += bb;
        }
    }
    float bs1[4], bso[4];
    #pragma unroll
    for (int g = 0; g < 4; ++g) bs1[g] = bd1[g * 64 + w * 16 + p];
    #pragma unroll
    for (int i = 0; i < 4; ++i) bso[i] = out_b[(w * 4 + i) * 16 + p];
    float c0[4] = {0.f, 0.f, 0.f, 0.f}, c1[4] = {0.f, 0.f, 0.f, 0.f};
    __syncthreads();

    for (int t = 0; t < T; ++t) {
        f32x4 acc[4];
        #pragma unroll
        for (int g = 0; g < 4; ++g) acc[g] = (f32x4){0.f, 0.f, 0.f, 0.f};
        #pragma unroll
        for (int kt = 0; kt < 2; ++kt) {
            f16x8 a = *(const f16x8*)&hdfrag[(kt * 64 + l) * 8];
            #pragma unroll
            for (int g = 0; g < 4; ++g)
                acc[g] = MFMA16(a, W0h[kt][g], acc[g]);
        }
        __syncthreads();
        #pragma unroll
        for (int r = 0; r < 4; ++r) {
            float iv = sigmoidf_(acc[0][r] + xz[0][r]);
            float fv = sigmoidf_(acc[1][r] + xz[1][r]);
            float gv = tanhf_(acc[2][r] + xz[2][r]);
            float ov = sigmoidf_(acc[3][r] + xz[3][r]);
            float cv = fv * c0[r] + iv * gv; c0[r] = cv;
            float hv = ov * tanhf_(cv);
            int j = w * 16 + p, b = q * 4 + r;
            hdfrag[((j >> 5) * 64 + ((j >> 3) & 3) * 16 + b) * 8 + (j & 7)] = (f16)hv;
        }
        __syncthreads();
        f32x4 acc1[4];
        #pragma unroll
        for (int g = 0; g < 4; ++g) acc1[g] = (f32x4){0.f, 0.f, 0.f, 0.f};
        #pragma unroll
        for (int kt = 0; kt < 4; ++kt) {
            f16x8 a = *(const f16x8*)&hdfrag[(kt * 64 + l) * 8];
            #pragma unroll
            for (int g = 0; g < 4; ++g)
                acc1[g] = MFMA16(a, W1[kt][g], acc1[g]);
        }
        __syncthreads();
        #pragma unroll
        for (int r = 0; r < 4; ++r) {
            float iv = sigmoidf_(acc1[0][r] + bs1[0]);
            float fv = sigmoidf_(acc1[1][r] + bs1[1]);
            float gv = tanhf_(acc1[2][r] + bs1[2]);
            float ov = sigmoidf_(acc1[3][r] + bs1[3]);
            float cv = fv * c1[r] + iv * gv; c1[r] = cv;
            float hv = ov * tanhf_(cv);
            int j = w * 16 + p, b = q * 4 + r;
            int k = 64 + j;
            hdfrag[((k >> 5) * 64 + ((k >> 3) & 3) * 16 + b) * 8 + (k & 7)] = (f16)hv;
        }
        __syncthreads();
        f32x4 acco[4];
        #pragma unroll
        for (int i = 0; i < 4; ++i) acco[i] = (f32x4){0.f, 0.f, 0.f, 0.f};
        #pragma unroll
        for (int kt = 0; kt < 2; ++kt) {
            f16x8 a = *(const f16x8*)&hdfrag[((2 + kt) * 64 + l) * 8];
            #pragma unroll
            for (int i = 0; i < 4; ++i)
                acco[i] = MFMA16(a, WO[kt][i], acco[i]);
        }
        #pragma unroll
        for (int i = 0; i < 4; ++i)
            #pragma unroll
            for (int r = 0; r < 4; ++r)
                __builtin_nontemporal_store(acco[i][r] + bso[i],
                    &out[((long)(b0 + q * 4 + r) * T + t) * 256 + (w * 4 + i) * 16 + p]);
    }
}

extern "C" void kernel_launch(void* const* d_in, const int* in_sizes, int n_in,
                              void* d_out, int out_size, void* d_ws, size_t ws_size,
                              hipStream_t stream)
{
    const float* x    = (const float*)d_in[0];
    const float* inW  = (const float*)d_in[1];
    const float* inb  = (const float*)d_in[2];
    const float* e0i  = (const float*)d_in[3];
    const float* e0h  = (const float*)d_in[4];
    const float* eb0i = (const float*)d_in[5];
    const float* eb0h = (const float*)d_in[6];
    const float* e1i  = (const float*)d_in[7];
    const float* e1h  = (const float*)d_in[8];
    const float* eb1i = (const float*)d_in[9];
    const float* eb1h = (const float*)d_in[10];
    const float* d0i  = (const float*)d_in[11];
    const float* d0h  = (const float*)d_in[12];
    const float* db0i = (const float*)d_in[13];
    const float* db0h = (const float*)d_in[14];
    const float* d1i  = (const float*)d_in[15];
    const float* d1h  = (const float*)d_in[16];
    const float* db1i = (const float*)d_in[17];
    const float* db1h = (const float*)d_in[18];
    const float* outW = (const float*)d_in[19];
    const float* outb = (const float*)d_in[20];

    char* ws = (char*)d_ws;
    f16*   pk     = (f16*)ws;
    float* biases = (float*)(ws + BIAS_OFF);
    int*   cnts   = (int*)(ws + CNT_OFF);
    f16*   h0f    = (f16*)(ws + H0F_OFF);
    f16*   ex1    = (f16*)(ws + EXCH1_OFF);
    f16*   zb     = (f16*)(ws + Z_OFF);
    f16*   h1x    = (f16*)(ws + H1X_OFF);
    float* out    = (float*)d_out;

    pack_kernel<<<502, 256, 0, stream>>>(inW, e0i, e0h, e1i, e1h, d0i, d0h, d1i, d1h, outW,
                                         eb0i, eb0h, eb1i, eb1h, db0i, db0h, db1i, db1h,
                                         pk, biases, cnts);
    inproj_kernel<<<6400, 256, 0, stream>>>(x, pk, inb, h0f);
    lstm_enc_kernel<2, false><<<256, 256, 0, stream>>>(h0f, pk + 16384, biases,
                                                       h1x, h1x, nullptr, cnts);
    lstm_enc_kernel<8, true ><<<256, 256, 0, stream>>>(h1x, pk + 344064, biases + 1024,
                                                       ex1, ex1, zb, cnts + 512);
    lstm_dec_kernel<<<64, 256, 0, stream>>>(zb, pk + 868352, pk + 933888, pk + 950272, pk + 983040,
                                            biases + 2048, biases + 2304, outb, out);
}

// Round 6
// 1997.190 us; speedup vs baseline: 6.3098x; 6.3098x over previous
//
#include <hip/hip_runtime.h>

typedef _Float16 f16;
typedef _Float16 f16x8 __attribute__((ext_vector_type(8)));
typedef float f32x4 __attribute__((ext_vector_type(4)));

#define MFMA16(a, b, c) __builtin_amdgcn_mfma_f32_16x16x32_f16((a), (b), (c), 0, 0, 0)

__device__ __forceinline__ float sigmoidf_(float x) { return 1.f / (1.f + __expf(-x)); }
__device__ __forceinline__ float tanhf_(float x) { return 1.f - 2.f / (__expf(2.f * x) + 1.f); }

// counted vmcnt wait + scheduler fence (rule #18: sched_barrier right after the wait,
// else hipcc hoists register-only MFMAs above the asm waitcnt)
template<int N> __device__ __forceinline__ void waitv();
#define DEFW(N) template<> __device__ __forceinline__ void waitv<N>() { \
    asm volatile("s_waitcnt vmcnt(" #N ")" ::: "memory"); \
    __builtin_amdgcn_sched_barrier(0); }
DEFW(0) DEFW(5) DEFW(8) DEFW(9) DEFW(10) DEFW(11)

// manual global load: compiler does not track it -> our vmcnt tables own the pipeline
#define GLD(dst, ptr, OFF) \
    asm volatile("global_load_dwordx4 %0, %1, off offset:" OFF : "=v"(dst) : "v"(ptr))

// ---- pipeline step macros (expand to pure constants; no lambdas/templates) ----
#define WISSUE(slot) do { \
    GLD(wf[slot][0], wq, "0");    GLD(wf[slot][1], wq, "1024"); \
    GLD(wf[slot][2], wq, "2048"); GLD(wf[slot][3], wq, "3072"); \
    wq += 32768; } while (0)

#define XISSUE(slot) do { GLD(xa[slot], xbp, "0"); xbp += 512; } while (0)

#define HSTEP(si, WT) do { \
    f16x8 a_ = *(const f16x8*)&hbp[((si) * 64 + l) * 8]; \
    waitv<WT>(); \
    acc[0] = MFMA16(a_, wf[(si) % 3][0], acc[0]); \
    acc[1] = MFMA16(a_, wf[(si) % 3][1], acc[1]); \
    acc[2] = MFMA16(a_, wf[(si) % 3][2], acc[2]); \
    acc[3] = MFMA16(a_, wf[(si) % 3][3], acc[3]); \
    __builtin_amdgcn_sched_barrier(0); } while (0)

#define XSTEP(si, slot, WT) do { \
    waitv<WT>(); \
    acc[0] = MFMA16(xa[slot], wf[(si) % 3][0], acc[0]); \
    acc[1] = MFMA16(xa[slot], wf[(si) % 3][1], acc[1]); \
    acc[2] = MFMA16(xa[slot], wf[(si) % 3][2], acc[2]); \
    acc[3] = MFMA16(xa[slot], wf[(si) % 3][3], acc[3]); \
    __builtin_amdgcn_sched_barrier(0); } while (0)

// ---------------- workspace layout (bytes) ----------------
// pk f16 weights 0..1998848 (elem offs: inW 0 | e0 16384 | e1 344064 | d0i 868352
//   | d0h 933888 | d1 950272 | out 983040)
// biases (2560 f32)  1998848
// h0f  [64][100][2][512] f16   2013184  (13.1MB)  enc0 x-frags
//   zb [1024][256] f16         2013184  (aliases h0f; h0f dead when enc1 runs)
// h1x  [64][100][8][512] f16  15120384  (52.4MB)  enc0 h-out == enc1 x-frags
#define BIAS_OFF   1998848
#define H0F_OFF    2013184
#define Z_OFF      2013184
#define H1X_OFF    15120384

// Fragment convention (gfx950 16x16x32 f16), lane la, elem e:
//   A: row = la&15,            k = kt*32 + (la>>4)*8 + e
//   B: n   = ntile*16+(la&15), k = kt*32 + (la>>4)*8 + e
// e-region pack layout (stage-major for the rec kernel's pipeline):
//   [si KT][w 16][g 4][lane 64][8]   stage si: si<8 = hh (k = ka+si*32), si>=8 = ih (k=(si-8)*32)
//   n = g*256 + w*16 + (lane&15)
// other regions (inW, d*): nt-major, g = (nt*KT + kt)*64 + lane (unchanged).

__global__ __launch_bounds__(256) void pack_kernel(
    const float* inW,
    const float* e0i, const float* e0h, const float* e1i, const float* e1h,
    const float* d0i, const float* d0h, const float* d1i, const float* d1h,
    const float* outW,
    const float* eb0i, const float* eb0h, const float* eb1i, const float* eb1h,
    const float* db0i, const float* db0h, const float* db1i, const float* db1h,
    f16* pk, float* bias_ws)
{
    int t = blockIdx.x * 256 + threadIdx.x;
    if (t < 124928) {
        int g = t; int KT, ka, kb, est; const float* A; const float* B; long doff;
        if (g < 2048)        {              KT = 8;  ka = 256; kb = 0;   est = 0; A = inW;  B = nullptr; doff = 0; }
        else if (g < 43008)  { g -= 2048;   KT = 10; ka = 64;  kb = 256; est = 1; A = e0i;  B = e0h;     doff = 16384; }
        else if (g < 108544) { g -= 43008;  KT = 16; ka = 256; kb = 256; est = 1; A = e1i;  B = e1h;     doff = 344064; }
        else if (g < 116736) { g -= 108544; KT = 8;  ka = 256; kb = 0;   est = 0; A = d0i;  B = nullptr; doff = 868352; }
        else if (g < 118784) { g -= 116736; KT = 2;  ka = 64;  kb = 0;   est = 0; A = d0h;  B = nullptr; doff = 933888; }
        else if (g < 122880) { g -= 118784; KT = 4;  ka = 64;  kb = 64;  est = 0; A = d1i;  B = d1h;     doff = 950272; }
        else                 { g -= 122880; KT = 2;  ka = 64;  kb = 0;   est = 0; A = outW; B = nullptr; doff = 983040; }
        int lane = g & 63;
        int n, k0;
        if (est) {   // stage-major e-region
            int rest = g >> 6;
            int gate = rest & 3, wv = (rest >> 2) & 15, si = rest >> 6;
            n  = gate * 256 + wv * 16 + (lane & 15);
            int kf = (lane >> 4) * 8;
            k0 = (si < 8) ? (ka + si * 32 + kf) : ((si - 8) * 32 + kf);
        } else {     // nt-major
            int gk = g >> 6;
            int kt = gk % KT, nt = gk / KT;
            n  = nt * 16 + (lane & 15);
            k0 = kt * 32 + (lane >> 4) * 8;
        }
        f16x8 v;
        #pragma unroll
        for (int j = 0; j < 8; ++j) {
            int k = k0 + j;
            float s = (k < ka) ? A[(long)n * ka + k] : B[(long)n * kb + (k - ka)];
            v[j] = (f16)s;
        }
        *(f16x8*)(pk + doff + (long)g * 8) = v;
    } else if (t < 127488) {
        int i = t - 124928;
        if (i < 1024)      bias_ws[i] = eb0i[i] + eb0h[i];
        else if (i < 2048) bias_ws[i] = eb1i[i - 1024] + eb1h[i - 1024];
        else if (i < 2304) bias_ws[i] = db0i[i - 2048] + db0h[i - 2048];
        else               bias_ws[i] = db1i[i - 2304] + db1h[i - 2304];
    }
}

// h0f = relu(x @ inW^T + in_b) in enc0 A-frag layout [bt][t][kt 2][lane][8].
// grid 6400 = bt(64) x t(100); 4 waves, wave w -> n-tile w.
__global__ __launch_bounds__(256) void inproj_kernel(
    const float* __restrict__ x, const f16* __restrict__ pkInW,
    const float* __restrict__ in_b, f16* __restrict__ h0f)
{
    int bt = blockIdx.x / 100, t = blockIdx.x % 100;
    int tid = threadIdx.x;
    int l = tid & 63, w = tid >> 6;
    int p = l & 15, q = l >> 4;
    f32x4 acc = {0.f, 0.f, 0.f, 0.f};
    const float* xrow = x + ((size_t)(bt * 16 + p) * 100 + t) * 256 + q * 8;
    const f16x8* bp = (const f16x8*)pkInW + w * 8 * 64 + l;
    #pragma unroll
    for (int kt = 0; kt < 8; ++kt) {
        const float4* xa = (const float4*)(xrow + kt * 32);
        float4 x0 = xa[0], x1 = xa[1];
        f16x8 a = {(f16)x0.x, (f16)x0.y, (f16)x0.z, (f16)x0.w,
                   (f16)x1.x, (f16)x1.y, (f16)x1.z, (f16)x1.w};
        acc = MFMA16(a, bp[kt * 64], acc);
    }
    int n = w * 16 + p;
    float bn = in_b[n];
    int lbase = q * 4 + ((w & 1) * 2 + (p >> 3)) * 16;
    f16* op = h0f + (((size_t)bt * 100 + t) * 2 + (w >> 1)) * 512 + lbase * 8 + (p & 7);
    #pragma unroll
    for (int r = 0; r < 4; ++r) {
        float v = acc[r] + bn;
        v = v > 0.f ? v : 0.f;
        op[r * 8] = (f16)v;
    }
}

// Persistent LSTM layer, intra-block recurrence: 64 blocks x 1024 thr (16 waves, 4/SIMD),
// block owns 16 batch rows for all T; wave w owns j-slice [w*16,w*16+16) x 4 gates.
// Weight stream (KT*64KB/ts, L2-resident) via depth-3 rotating register pipeline:
// asm global_load_dwordx4 + hand-counted s_waitcnt vmcnt(N) (position-derived tables,
// never 0 except the last stage) -> ~11 stages x 16 waves ~ 180KB in flight per CU.
// x-frags issued staggered (one per stage, 4-slot rotation) to cap VGPR liveness.
// Next-t weight prologue hoisted before the pointwise (addresses are t-invariant), so
// refill latency hides under the transcendentals. Tables are store-offset-invariant:
// WSEQ's 4 stores shift issue positions and outstanding counts equally.
// h in 2x8KB LDS double buffer; ONE raw s_barrier (+lgkmcnt(0)) per ts.
template <int KTX, bool WSEQ>
__global__ __launch_bounds__(1024, 4) void lstm_rec_kernel(
    const f16* __restrict__ xsrc,   // [64][100][KTX][512] f16 A-frags
    const f16* __restrict__ pkW,    // [KT][16][4][64][8]
    const float* __restrict__ bias, // [1024]
    f16* __restrict__ hseq,         // WSEQ: [64][100][8][512] A-frags
    f16* __restrict__ zout)         // !WSEQ: [1024][256] row-major
{
    constexpr int KT = KTX + 8;
    constexpr int T = 100;
    __shared__ __align__(16) f16 hfrag[2][4096];
    int tid = threadIdx.x, l = tid & 63, w = tid >> 6, p = l & 15, q = l >> 4;
    int bt = blockIdx.x;

    for (int i = tid; i < 4096; i += 1024) hfrag[1][i] = (f16)0.f;

    float bs[4];
    #pragma unroll
    for (int g = 0; g < 4; ++g) bs[g] = bias[g * 256 + w * 16 + p];
    float c[4] = {0.f, 0.f, 0.f, 0.f};

    const f16* wwave = pkW + (size_t)w * 2048 + (size_t)l * 8;  // stage stride 32768 elems
    int lbase = q * 4 + ((w & 1) * 2 + (p >> 3)) * 16;
    int hwidx = ((w >> 1) * 64 + lbase) * 8 + (p & 7);          // LDS h-write base (+r*8)
    __syncthreads();

    f16x8 wf[3][4];     // rotating weight stages (persist across t: prologue is hoisted)
    f16x8 xa[4];        // rotating x fragments
    const f16* wq = wwave;
    WISSUE(0); WISSUE(1); WISSUE(2);   // S0,S1,S2 for t=0

    for (int t = 0; t < T; ++t) {
        const f16* hbp = hfrag[(t & 1) ^ 1];
        f16* hw = hfrag[t & 1];
        const f16* xbp = xsrc + ((size_t)bt * T + t) * (KTX * 512) + (size_t)l * 8;

        f32x4 acc[4];
        #pragma unroll
        for (int g = 0; g < 4; ++g) acc[g] = (f32x4){0.f, 0.f, 0.f, 0.f};

        if constexpr (KTX == 2) {
            // KT=10.  Issue: S0-2 | it0:S3 | it1:S4 | it2:S5 | it3:S6 | it4:S7,X0
            //               | it5:S8,X1 | it6:S9.  Positions: S7:32 X0:33 S8:37 X1:38 S9:42.
            HSTEP(0, 8);  WISSUE(0);
            HSTEP(1, 8);  WISSUE(1);
            HSTEP(2, 8);  WISSUE(2);
            HSTEP(3, 8);  WISSUE(0);
            HSTEP(4, 8);  WISSUE(1); XISSUE(0);
            HSTEP(5, 9);  WISSUE(2); XISSUE(1);
            HSTEP(6, 10); WISSUE(0);
            HSTEP(7, 10);
            XSTEP(8, 0, 5);
            XSTEP(9, 1, 0);
        } else {
            // KT=16.  Issue: S0-2 | it k: S(k+3) (k<=12) | it 4+i: X_i (i=0..7).
            // Positions: S7:32 X0:33 S8:37 X1:38 ... S13:62 X6:63 S14:67 X7:68 S15:72.
            HSTEP(0, 8);   WISSUE(0);
            HSTEP(1, 8);   WISSUE(1);
            HSTEP(2, 8);   WISSUE(2);
            HSTEP(3, 8);   WISSUE(0);
            HSTEP(4, 8);   WISSUE(1); XISSUE(0);
            HSTEP(5, 9);   WISSUE(2); XISSUE(1);
            HSTEP(6, 10);  WISSUE(0); XISSUE(2);
            HSTEP(7, 11);  WISSUE(1); XISSUE(3);
            XSTEP(8, 0, 11);  WISSUE(2); XISSUE(0);   // X4 -> slot 0
            XSTEP(9, 1, 11);  WISSUE(0); XISSUE(1);   // X5 -> slot 1
            XSTEP(10, 2, 11); WISSUE(1); XISSUE(2);   // X6 -> slot 2
            XSTEP(11, 3, 11); WISSUE(2); XISSUE(3);   // X7 -> slot 3
            XSTEP(12, 0, 11); WISSUE(0);              // S15 -> slot 0
            XSTEP(13, 1, 10);
            XSTEP(14, 2, 5);
            XSTEP(15, 3, 0);
        }

        // hoisted next-t weight prologue (t-invariant addresses; vmcnt==0 here)
        wq = wwave;
        if (t + 1 < T) { WISSUE(0); WISSUE(1); WISSUE(2); }

        // pointwise (in-lane: row q*4+r, col j = w*16+p), h -> LDS (+ global if WSEQ)
        f16* op = nullptr;
        if constexpr (WSEQ)
            op = hseq + (((size_t)bt * T + t) * 8 + (w >> 1)) * 512 + lbase * 8 + (p & 7);
        #pragma unroll
        for (int r = 0; r < 4; ++r) {
            float iv = sigmoidf_(acc[0][r] + bs[0]);
            float fv = sigmoidf_(acc[1][r] + bs[1]);
            float gv = tanhf_(acc[2][r] + bs[2]);
            float ov = sigmoidf_(acc[3][r] + bs[3]);
            float cv = fv * c[r] + iv * gv; c[r] = cv;
            float hv = ov * tanhf_(cv);
            f16 hb16 = (f16)hv;
            hw[hwidx + r * 8] = hb16;
            if constexpr (WSEQ) __builtin_nontemporal_store(hb16, &op[r * 8]);
            else if (t == T - 1)
                zout[(size_t)(bt * 16 + q * 4 + r) * 256 + w * 16 + p] = hb16;
        }
        asm volatile("s_waitcnt lgkmcnt(0)" ::: "memory");  // h LDS writes committed
        __builtin_amdgcn_sched_barrier(0);
        __builtin_amdgcn_s_barrier();                       // raw: no vmcnt drain
    }
}

// Fused decoder: dec0 (z-proj constant over t in regs) + dec1 + output projection.
// 64 blocks x 256 threads; all recurrent weights register-resident; inner loop global-free.
__global__ __launch_bounds__(256, 1) void lstm_dec_kernel(
    const f16* __restrict__ z,
    const f16* __restrict__ pkD0i, const f16* __restrict__ pkD0h,
    const f16* __restrict__ pkD1,  const f16* __restrict__ pkOut,
    const float* __restrict__ bd0, const float* __restrict__ bd1,
    const float* __restrict__ out_b, float* __restrict__ out)
{
    constexpr int T = 100;
    __shared__ __align__(16) f16 hdfrag[4 * 64 * 8];
    int tid = threadIdx.x;
    int l = tid & 63, w = tid >> 6;
    int p = l & 15, q = l >> 4;
    int b0 = blockIdx.x * 16;

    for (int i = tid; i < 2048; i += 256) hdfrag[i] = (f16)0.f;

    f16x8 W0h[2][4], W1[4][4], WO[2][4];
    #pragma unroll
    for (int g = 0; g < 4; ++g) {
        #pragma unroll
        for (int kt = 0; kt < 2; ++kt)
            W0h[kt][g] = ((const f16x8*)pkD0h)[(((g * 4 + w) * 2 + kt) * 64) + l];
        #pragma unroll
        for (int kt = 0; kt < 4; ++kt)
            W1[kt][g] = ((const f16x8*)pkD1)[(((g * 4 + w) * 4 + kt) * 64) + l];
    }
    #pragma unroll
    for (int i = 0; i < 4; ++i)
        #pragma unroll
        for (int kt = 0; kt < 2; ++kt)
            WO[kt][i] = ((const f16x8*)pkOut)[(((w * 4 + i) * 2 + kt) * 64) + l];

    f32x4 xz[4];
    #pragma unroll
    for (int g = 0; g < 4; ++g) xz[g] = (f32x4){0.f, 0.f, 0.f, 0.f};
    {
        const f16x8* zp = (const f16x8*)z + (long)(b0 + p) * 32 + q;
        const f16x8* wp = (const f16x8*)pkD0i + l;
        #pragma unroll
        for (int kt = 0; kt < 8; ++kt) {
            f16x8 a = zp[kt * 4];
            #pragma unroll
            for (int g = 0; g < 4; ++g)
                xz[g] = MFMA16(a, wp[((g * 4 + w) * 8 + kt) * 64], xz[g]);
        }
        #pragma unroll
        for (int g = 0; g < 4; ++g) {
            float bb = bd0[g * 64 + w * 16 + p];
            #pragma unroll
            for (int r = 0; r < 4; ++r) xz[g][r] += bb;
        }
    }
    float bs1[4], bso[4];
    #pragma unroll
    for (int g = 0; g < 4; ++g) bs1[g] = bd1[g * 64 + w * 16 + p];
    #pragma unroll
    for (int i = 0; i < 4; ++i) bso[i] = out_b[(w * 4 + i) * 16 + p];
    float c0[4] = {0.f, 0.f, 0.f, 0.f}, c1[4] = {0.f, 0.f, 0.f, 0.f};
    __syncthreads();

    for (int t = 0; t < T; ++t) {
        f32x4 acc[4];
        #pragma unroll
        for (int g = 0; g < 4; ++g) acc[g] = (f32x4){0.f, 0.f, 0.f, 0.f};
        #pragma unroll
        for (int kt = 0; kt < 2; ++kt) {
            f16x8 a = *(const f16x8*)&hdfrag[(kt * 64 + l) * 8];
            #pragma unroll
            for (int g = 0; g < 4; ++g)
                acc[g] = MFMA16(a, W0h[kt][g], acc[g]);
        }
        __syncthreads();
        #pragma unroll
        for (int r = 0; r < 4; ++r) {
            float iv = sigmoidf_(acc[0][r] + xz[0][r]);
            float fv = sigmoidf_(acc[1][r] + xz[1][r]);
            float gv = tanhf_(acc[2][r] + xz[2][r]);
            float ov = sigmoidf_(acc[3][r] + xz[3][r]);
            float cv = fv * c0[r] + iv * gv; c0[r] = cv;
            float hv = ov * tanhf_(cv);
            int j = w * 16 + p, b = q * 4 + r;
            hdfrag[((j >> 5) * 64 + ((j >> 3) & 3) * 16 + b) * 8 + (j & 7)] = (f16)hv;
        }
        __syncthreads();
        f32x4 acc1[4];
        #pragma unroll
        for (int g = 0; g < 4; ++g) acc1[g] = (f32x4){0.f, 0.f, 0.f, 0.f};
        #pragma unroll
        for (int kt = 0; kt < 4; ++kt) {
            f16x8 a = *(const f16x8*)&hdfrag[(kt * 64 + l) * 8];
            #pragma unroll
            for (int g = 0; g < 4; ++g)
                acc1[g] = MFMA16(a, W1[kt][g], acc1[g]);
        }
        __syncthreads();
        #pragma unroll
        for (int r = 0; r < 4; ++r) {
            float iv = sigmoidf_(acc1[0][r] + bs1[0]);
            float fv = sigmoidf_(acc1[1][r] + bs1[1]);
            float gv = tanhf_(acc1[2][r] + bs1[2]);
            float ov = sigmoidf_(acc1[3][r] + bs1[3]);
            float cv = fv * c1[r] + iv * gv; c1[r] = cv;
            float hv = ov * tanhf_(cv);
            int j = w * 16 + p, b = q * 4 + r;
            int k = 64 + j;
            hdfrag[((k >> 5) * 64 + ((k >> 3) & 3) * 16 + b) * 8 + (k & 7)] = (f16)hv;
        }
        __syncthreads();
        f32x4 acco[4];
        #pragma unroll
        for (int i = 0; i < 4; ++i) acco[i] = (f32x4){0.f, 0.f, 0.f, 0.f};
        #pragma unroll
        for (int kt = 0; kt < 2; ++kt) {
            f16x8 a = *(const f16x8*)&hdfrag[((2 + kt) * 64 + l) * 8];
            #pragma unroll
            for (int i = 0; i < 4; ++i)
                acco[i] = MFMA16(a, WO[kt][i], acco[i]);
        }
        #pragma unroll
        for (int i = 0; i < 4; ++i)
            #pragma unroll
            for (int r = 0; r < 4; ++r)
                __builtin_nontemporal_store(acco[i][r] + bso[i],
                    &out[((long)(b0 + q * 4 + r) * T + t) * 256 + (w * 4 + i) * 16 + p]);
    }
}

extern "C" void kernel_launch(void* const* d_in, const int* in_sizes, int n_in,
                              void* d_out, int out_size, void* d_ws, size_t ws_size,
                              hipStream_t stream)
{
    const float* x    = (const float*)d_in[0];
    const float* inW  = (const float*)d_in[1];
    const float* inb  = (const float*)d_in[2];
    const float* e0i  = (const float*)d_in[3];
    const float* e0h  = (const float*)d_in[4];
    const float* eb0i = (const float*)d_in[5];
    const float* eb0h = (const float*)d_in[6];
    const float* e1i  = (const float*)d_in[7];
    const float* e1h  = (const float*)d_in[8];
    const float* eb1i = (const float*)d_in[9];
    const float* eb1h = (const float*)d_in[10];
    const float* d0i  = (const float*)d_in[11];
    const float* d0h  = (const float*)d_in[12];
    const float* db0i = (const float*)d_in[13];
    const float* db0h = (const float*)d_in[14];
    const float* d1i  = (const float*)d_in[15];
    const float* d1h  = (const float*)d_in[16];
    const float* db1i = (const float*)d_in[17];
    const float* db1h = (const float*)d_in[18];
    const float* outW = (const float*)d_in[19];
    const float* outb = (const float*)d_in[20];

    char* ws = (char*)d_ws;
    f16*   pk     = (f16*)ws;
    float* biases = (float*)(ws + BIAS_OFF);
    f16*   h0f    = (f16*)(ws + H0F_OFF);
    f16*   zb     = (f16*)(ws + Z_OFF);
    f16*   h1x    = (f16*)(ws + H1X_OFF);
    float* out    = (float*)d_out;

    pack_kernel<<<498, 256, 0, stream>>>(inW, e0i, e0h, e1i, e1h, d0i, d0h, d1i, d1h, outW,
                                         eb0i, eb0h, eb1i, eb1h, db0i, db0h, db1i, db1h,
                                         pk, biases);
    inproj_kernel<<<6400, 256, 0, stream>>>(x, pk, inb, h0f);
    lstm_rec_kernel<2, true ><<<64, 1024, 0, stream>>>(h0f, pk + 16384, biases, h1x, nullptr);
    lstm_rec_kernel<8, false><<<64, 1024, 0, stream>>>(h1x, pk + 344064, biases + 1024, nullptr, zb);
    lstm_dec_kernel<<<64, 256, 0, stream>>>(zb, pk + 868352, pk + 933888, pk + 950272, pk + 983040,
                                            biases + 2048, biases + 2304, outb, out);
}